// Round 8
// baseline (242.928 us; speedup 1.0000x reference)
//
#include <hip/hip_runtime.h>

typedef unsigned short u16;
typedef unsigned int u32;
typedef __attribute__((ext_vector_type(8))) short short8;
typedef __attribute__((ext_vector_type(4))) short s16x4;
typedef __attribute__((ext_vector_type(4))) float f32x4;

__device__ __forceinline__ float b2f(u16 u) {
    union { u32 i; float f; } v; v.i = ((u32)u) << 16; return v.f;
}
__device__ __forceinline__ u16 f2b(float f) {
    union { u32 i; float f; } v; v.f = f;
    u32 u = v.i;
    return (u16)((u + 0x7FFFu + ((u >> 16) & 1u)) >> 16);
}
__device__ __forceinline__ f32x4 zero4() {
    f32x4 v; v[0] = 0.f; v[1] = 0.f; v[2] = 0.f; v[3] = 0.f; return v;
}
// packed f32x2 -> bf16x2 (RNE); low 16 bits = first arg (HW-verified R13/R15)
__device__ __forceinline__ u32 cvtpk(float lo, float hi) {
    u32 d;
    asm("v_cvt_pk_bf16_f32 %0, %1, %2" : "=v"(d) : "v"(lo), "v"(hi));
    return d;
}
__device__ __forceinline__ float fexp2(float x) {
#if __has_builtin(__builtin_amdgcn_exp2f)
    return __builtin_amdgcn_exp2f(x);
#else
    return __expf(x * 0.6931471805599453f);
#endif
}
// async global->LDS, 16B per lane: lane l's 16B land at ldsbase + l*16.
__device__ __forceinline__ void gload16(const u16* g, u16* l) {
    __builtin_amdgcn_global_load_lds(
        (const __attribute__((address_space(1))) u32*)g,
        (__attribute__((address_space(3))) u32*)l, 16, 0, 0);
}

// ---------------------------------------------------------------------------
// Merged prep kernel (verified R18).
// blocks [0,432):   Wqkv fp32 [768][2304] -> bf16 [2304][768] transpose
// blocks [432,576): Wproj fp32 [768][768] -> bf16 [768][768] transpose
// blocks [576,1152): x fp32 -> bf16 linear convert (grid-stride)
// ---------------------------------------------------------------------------
__device__ __forceinline__ void tconv_body(const float* __restrict__ src,
                                           u16* __restrict__ dst,
                                           int K, int N, int bx, int by) {
    __shared__ u16 T[64][72];
    const int n0 = bx * 64, k0 = by * 64;
    const int tid = threadIdx.x;
    const int r = tid >> 3, cq = tid & 7;   // r: 0..31, cq: 0..7
#pragma unroll
    for (int half = 0; half < 2; half++) {
        const int k = k0 + half * 32 + r;
        const float* s = &src[(size_t)k * N + n0 + cq * 8];
        const float4 f0 = ((const float4*)s)[0];
        const float4 f1 = ((const float4*)s)[1];
        T[cq * 8 + 0][half * 32 + r] = f2b(f0.x);
        T[cq * 8 + 1][half * 32 + r] = f2b(f0.y);
        T[cq * 8 + 2][half * 32 + r] = f2b(f0.z);
        T[cq * 8 + 3][half * 32 + r] = f2b(f0.w);
        T[cq * 8 + 4][half * 32 + r] = f2b(f1.x);
        T[cq * 8 + 5][half * 32 + r] = f2b(f1.y);
        T[cq * 8 + 6][half * 32 + r] = f2b(f1.z);
        T[cq * 8 + 7][half * 32 + r] = f2b(f1.w);
    }
    __syncthreads();
#pragma unroll
    for (int half = 0; half < 2; half++) {
        const int n = half * 32 + r;
        short8 o = *(const short8*)&T[n][cq * 8];
        *(short8*)&dst[(size_t)(n0 + n) * K + k0 + cq * 8] = o;
    }
}

__global__ void prep_kernel(const float* __restrict__ x, u16* __restrict__ xb,
                            const float* __restrict__ Wqkv, u16* __restrict__ Wqkvb,
                            const float* __restrict__ Wproj, u16* __restrict__ Wprojb,
                            int n8x) {
    const int blk = blockIdx.x;
    if (blk < 432) {
        tconv_body(Wqkv, Wqkvb, 768, 2304, blk % 36, blk / 36);
    } else if (blk < 576) {
        const int id = blk - 432;
        tconv_body(Wproj, Wprojb, 768, 768, id % 12, id / 12);
    } else {
        const int stride = (1152 - 576) * 256;
        for (int i = (blk - 576) * 256 + threadIdx.x; i < n8x; i += stride) {
            const float* s = x + (size_t)i * 8;
            float4 a = ((const float4*)s)[0];
            float4 b = ((const float4*)s)[1];
            short8 o;
            o[0] = (short)f2b(a.x); o[1] = (short)f2b(a.y);
            o[2] = (short)f2b(a.z); o[3] = (short)f2b(a.w);
            o[4] = (short)f2b(b.x); o[5] = (short)f2b(b.y);
            o[6] = (short)f2b(b.z); o[7] = (short)f2b(b.w);
            ((short8*)xb)[i] = o;
        }
    }
}

// ---------------------------------------------------------------------------
// GEMM, R19: BK=64 + chunk-parity swizzle (verified R18) + two new levers:
//  1. T3-minimum 2-phase double-buffer + T4 counted vmcnt: stage tile t+1
//     into buf^1 BEFORE computing tile t; s_waitcnt vmcnt(8) (not 0) keeps
//     next-tile loads in flight across the RAW s_barrier (no __syncthreads
//     drain). Per-wave outstanding: 8 current + 8 next -> vmcnt(8) drains
//     exactly the current tile. Load latency hides under 32 MFMA + 16
//     ds_read of the previous tile.
//  2. Swapped-operand epilogue (mfma(bfr, af), trick verified in R15/R16):
//     C per-reg index = n-dim, per-lane = m-dim -> each lane holds 4
//     CONSECUTIVE output columns: MODE 0 writes 16 uint2 (cvtpk pairs)
//     instead of 64 scalar u16 + 64 f2b; MODE 1 writes 16 float4 instead
//     of 64 scalar f32. gcb = n0+wn+ni*16+quad*4 is 4-aligned and never
//     crosses a 768- or 64-boundary -> which/hh uniform per (ni,lane).
// LDS 64 KB -> 2 blocks/CU. XCD swizzle (T1): nwg 1152/384, both %8==0.
// ---------------------------------------------------------------------------
template <int MODE>
__global__ __launch_bounds__(256, 2) void gemm_bt_kernel(
    const u16* __restrict__ A, const u16* __restrict__ Bt,
    const float* __restrict__ bias,
    u16* __restrict__ O0, u16* __restrict__ O1, u16* __restrict__ O2,
    float* __restrict__ Of,
    int M, int N, int K)
{
    __shared__ u16 As[2][128 * 64];   // double-buffered, linear+swizzled
    __shared__ u16 Bs[2][128 * 64];

    const int tid = threadIdx.x;
    const int nwgx = gridDim.x;
    const int nwg = nwgx * gridDim.y;
    int lin = blockIdx.y * nwgx + blockIdx.x;
    lin = (lin & 7) * (nwg >> 3) + (lin >> 3);   // bijective: nwg % 8 == 0
    const int m0 = (lin / nwgx) * 128, n0 = (lin % nwgx) * 128;
    const int lane = tid & 63, w = tid >> 6;
    const int quad = lane >> 4, c = lane & 15;
    const int wm = (w & 1) * 64, wn = (w >> 1) * 64;

    f32x4 acc[4][4];
#pragma unroll
    for (int i = 0; i < 4; i++)
#pragma unroll
        for (int j = 0; j < 4; j++) acc[i][j] = zero4();

    // staging: wave w covers rows [w*32, w*32+32) x 64 k per tile.
    // instr i: 8 rows (w*32+i*8+(lane>>3)), source col pre-swizzled (R18).
    const int srow = lane >> 3;                         // 0..7
    const int scol = ((lane & 7) ^ ((srow & 1) << 2)) * 8;  // pre-swizzled
    const size_t abase = (size_t)(m0 + w * 32 + srow) * K + scol;
    const size_t bbase = (size_t)(n0 + w * 32 + srow) * K + scol;

    const int cpar = (c & 1) << 2;   // read-side swizzle term

    // prologue: stage tile 0 -> buf 0 (loads left in flight)
    {
        u16* asl = &As[0][w * 2048];
        u16* bsl = &Bs[0][w * 2048];
#pragma unroll
        for (int i = 0; i < 4; i++)
            gload16(A + abase + (size_t)(i * 8) * K, asl + i * 512);
#pragma unroll
        for (int i = 0; i < 4; i++)
            gload16(Bt + bbase + (size_t)(i * 8) * K, bsl + i * 512);
    }

    const int niter = K >> 6;
    int cur = 0;
    for (int it = 0; it < niter; it++) {
        asm volatile("" ::: "memory");
        __builtin_amdgcn_s_barrier();     // prev iter's frag reads retired
        asm volatile("" ::: "memory");
        if (it + 1 < niter) {             // stage next tile into other buffer
            const size_t k1 = (size_t)(it + 1) * 64;
            u16* asl = &As[cur ^ 1][w * 2048];
            u16* bsl = &Bs[cur ^ 1][w * 2048];
#pragma unroll
            for (int i = 0; i < 4; i++)
                gload16(A + abase + (size_t)(i * 8) * K + k1, asl + i * 512);
#pragma unroll
            for (int i = 0; i < 4; i++)
                gload16(Bt + bbase + (size_t)(i * 8) * K + k1, bsl + i * 512);
            // counted: drain the 8 oldest (current tile); next 8 stay in flight
            asm volatile("s_waitcnt vmcnt(8)" ::: "memory");
        } else {
            asm volatile("s_waitcnt vmcnt(0)" ::: "memory");
        }
        __builtin_amdgcn_s_barrier();     // all waves' current tile landed
        asm volatile("" ::: "memory");

        short8 af[4][2], bfr[4][2];
#pragma unroll
        for (int mi = 0; mi < 4; mi++)
#pragma unroll
            for (int kk = 0; kk < 2; kk++)
                af[mi][kk] = *(const short8*)
                    &As[cur][(wm + mi * 16 + c) * 64 + (((kk * 4 + quad) ^ cpar) * 8)];
#pragma unroll
        for (int ni = 0; ni < 4; ni++)
#pragma unroll
            for (int kk = 0; kk < 2; kk++)
                bfr[ni][kk] = *(const short8*)
                    &Bs[cur][(wn + ni * 16 + c) * 64 + (((kk * 4 + quad) ^ cpar) * 8)];
#pragma unroll
        for (int kk = 0; kk < 2; kk++)
#pragma unroll
            for (int mi = 0; mi < 4; mi++)
#pragma unroll
                for (int ni = 0; ni < 4; ni++)
                    acc[mi][ni] = __builtin_amdgcn_mfma_f32_16x16x32_bf16(
                        bfr[ni][kk], af[mi][kk], acc[mi][ni], 0, 0, 0);
        cur ^= 1;
    }

    // swapped-C epilogue: acc[mi][ni][r] = C[n = wn+ni*16+quad*4+r][m = wm+mi*16+c]
#pragma unroll
    for (int ni = 0; ni < 4; ni++) {
        const int gcb = n0 + wn + ni * 16 + quad * 4;   // 4 consecutive cols
        const f32x4 bv = *(const f32x4*)&bias[gcb];
        if (MODE == 0) {
            const int which = gcb / 768;                 // uniform across the 4
            const int e = gcb - which * 768;
            const int hh = e >> 6, d = e & 63;           // d..d+3, no crossing
            u16* op = (which == 0) ? O0 : (which == 1 ? O1 : O2);
#pragma unroll
            for (int mi = 0; mi < 4; mi++) {
                const int gr = m0 + wm + mi * 16 + c;    // seq row (per-lane)
                const int bb = gr >> 11, s = gr & 2047;
                uint2 pk;
                pk.x = cvtpk(acc[mi][ni][0] + bv[0], acc[mi][ni][1] + bv[1]);
                pk.y = cvtpk(acc[mi][ni][2] + bv[2], acc[mi][ni][3] + bv[3]);
                *(uint2*)&op[(((size_t)bb * 12 + hh) * 2048 + s) * 64 + d] = pk;
            }
        } else {
#pragma unroll
            for (int mi = 0; mi < 4; mi++) {
                const int gr = m0 + wm + mi * 16 + c;
                float4 o;
                o.x = acc[mi][ni][0] + bv[0];
                o.y = acc[mi][ni][1] + bv[1];
                o.z = acc[mi][ni][2] + bv[2];
                o.w = acc[mi][ni][3] + bv[3];
                *(float4*)&Of[(size_t)gr * N + gcb] = o;
            }
        }
    }
}

// ---------------------------------------------------------------------------
// Flash attention — UNCHANGED from R17/R18 (verified passing, ~90 us):
// 128 q-rows/block (2 groups/wave), swapped QK^T, cvtpk+b64 P stores,
// exp2-domain mask bias, T14 prefetch with raw barriers, T5 setprio.
// Multi-pipe saturated for this structure; frozen.
// ---------------------------------------------------------------------------
__global__ __launch_bounds__(256, 3) void attn_kernel(
    const u16* __restrict__ Q, const u16* __restrict__ Kv,
    const u16* __restrict__ Vv, const int* __restrict__ attmask,
    u16* __restrict__ Y)
{
    const int S = 2048, D = 64, NH = 12;
    __shared__ u16 Ks[64][72];          // [pos][d]
    __shared__ u16 Vs[64][68];          // [d][pos]
    __shared__ u16 Ps[4][2][16][72];    // per-wave,per-group P: [qrow][pos]
    __shared__ float msf[2048];         // exp2-domain mask bias: 0 or -43282

    const int tid = threadIdx.x;
    const int w = tid >> 6, lane = tid & 63;
    const int quad = lane >> 4, c = lane & 15;
    const int bh = blockIdx.x;        // 0..47
    const int qt = blockIdx.y;        // 0..15
    const int b = bh / NH, h = bh - b * NH;

    const u16* Qh = Q + (size_t)bh * S * D;
    const u16* Kh = Kv + (size_t)bh * S * D;
    const u16* Vh = Vv + (size_t)bh * S * D;
    const int q0 = qt * 128 + w * 16;   // group 0; group 1 at q0+64

    short8 aq00 = *(const short8*)&Qh[(size_t)(q0 + c) * D + quad * 8];
    short8 aq01 = *(const short8*)&Qh[(size_t)(q0 + c) * D + 32 + quad * 8];
    short8 aq10 = *(const short8*)&Qh[(size_t)(q0 + 64 + c) * D + quad * 8];
    short8 aq11 = *(const short8*)&Qh[(size_t)(q0 + 64 + c) * D + 32 + quad * 8];

    for (int i = tid; i < S; i += 256)
        msf[i] = (attmask[b * S + i] == 0) ? -43282.0f : 0.0f;

    f32x4 o_acc[2][4];
#pragma unroll
    for (int g = 0; g < 2; g++)
#pragma unroll
        for (int i = 0; i < 4; i++) o_acc[g][i] = zero4();
    float l0 = 0.f, l1 = 0.f;

    const int kpos = tid >> 2, kd = (tid & 3) * 8;
    const int p2 = tid >> 3, vd = (tid & 7) * 8;

    // T14 prologue: issue tile-0 loads
    short8 k0r = *(const short8*)&Kh[(size_t)kpos * D + kd];
    short8 k1r = *(const short8*)&Kh[(size_t)kpos * D + kd + 32];
    short8 v0r = *(const short8*)&Vh[(size_t)(2 * p2) * D + vd];
    short8 v1r = *(const short8*)&Vh[(size_t)(2 * p2 + 1) * D + vd];

    const float SC = 0.18033688f;  // 0.125 * log2(e)

    for (int kt = 0; kt < S / 64; kt++) {
        // ---- staging (raw barriers: vmcnt NOT drained -> prefetch in flight)
        asm volatile("" ::: "memory");
        __builtin_amdgcn_s_barrier();
        asm volatile("" ::: "memory");
        *(short8*)&Ks[kpos][kd] = k0r;
        *(short8*)&Ks[kpos][kd + 32] = k1r;
#pragma unroll
        for (int j = 0; j < 8; j++) {
            u32 pk = (u32)(u16)v0r[j] | ((u32)(u16)v1r[j] << 16);
            *(u32*)&Vs[vd + j][2 * p2] = pk;
        }
        if (kt + 1 < S / 64) {
            const int nb = (kt + 1) * 64;
            k0r = *(const short8*)&Kh[(size_t)(nb + kpos) * D + kd];
            k1r = *(const short8*)&Kh[(size_t)(nb + kpos) * D + kd + 32];
            v0r = *(const short8*)&Vh[(size_t)(nb + 2 * p2) * D + vd];
            v1r = *(const short8*)&Vh[(size_t)(nb + 2 * p2 + 1) * D + vd];
        }
        asm volatile("s_waitcnt lgkmcnt(0)" ::: "memory");
        __builtin_amdgcn_s_barrier();
        asm volatile("" ::: "memory");

        const int kbase = kt * 64;

        // ---- QK^T, swapped: s[g][ni] = S[kpos=ni*16+quad*4+r][q-group g]
        f32x4 s0[4], s1[4];
#pragma unroll
        for (int ni = 0; ni < 4; ni++) { s0[ni] = zero4(); s1[ni] = zero4(); }
        __builtin_amdgcn_s_setprio(1);
#pragma unroll
        for (int ni = 0; ni < 4; ni++) {
            short8 bk0 = *(const short8*)&Ks[ni * 16 + c][quad * 8];
            short8 bk1 = *(const short8*)&Ks[ni * 16 + c][32 + quad * 8];
            s0[ni] = __builtin_amdgcn_mfma_f32_16x16x32_bf16(bk0, aq00, s0[ni], 0, 0, 0);
            s0[ni] = __builtin_amdgcn_mfma_f32_16x16x32_bf16(bk1, aq01, s0[ni], 0, 0, 0);
            s1[ni] = __builtin_amdgcn_mfma_f32_16x16x32_bf16(bk0, aq10, s1[ni], 0, 0, 0);
            s1[ni] = __builtin_amdgcn_mfma_f32_16x16x32_bf16(bk1, aq11, s1[ni], 0, 0, 0);
        }
        __builtin_amdgcn_s_setprio(0);

        // ---- softmax per group: cvtpk pairs + one b64 store per (g,ni) ----
#pragma unroll
        for (int ni = 0; ni < 4; ni++) {
            const f32x4 bias = *(const f32x4*)&msf[kbase + ni * 16 + quad * 4];
            {
                float p0 = fexp2(fmaf(s0[ni][0], SC, bias[0]));
                float p1 = fexp2(fmaf(s0[ni][1], SC, bias[1]));
                float p2f = fexp2(fmaf(s0[ni][2], SC, bias[2]));
                float p3 = fexp2(fmaf(s0[ni][3], SC, bias[3]));
                l0 += (p0 + p1) + (p2f + p3);
                uint2 pk;
                pk.x = cvtpk(p0, p1);
                pk.y = cvtpk(p2f, p3);
                *(uint2*)&Ps[w][0][c][ni * 16 + quad * 4] = pk;
            }
            {
                float p0 = fexp2(fmaf(s1[ni][0], SC, bias[0]));
                float p1 = fexp2(fmaf(s1[ni][1], SC, bias[1]));
                float p2f = fexp2(fmaf(s1[ni][2], SC, bias[2]));
                float p3 = fexp2(fmaf(s1[ni][3], SC, bias[3]));
                l1 += (p0 + p1) + (p2f + p3);
                uint2 pk;
                pk.x = cvtpk(p0, p1);
                pk.y = cvtpk(p2f, p3);
                *(uint2*)&Ps[w][1][c][ni * 16 + quad * 4] = pk;
            }
        }
        // Ps is per-wave: in-order DS pipeline orders stores before our reads.

        short8 ap00 = *(const short8*)&Ps[w][0][c][quad * 8];
        short8 ap01 = *(const short8*)&Ps[w][0][c][32 + quad * 8];
        short8 ap10 = *(const short8*)&Ps[w][1][c][quad * 8];
        short8 ap11 = *(const short8*)&Ps[w][1][c][32 + quad * 8];
        __builtin_amdgcn_s_setprio(1);
#pragma unroll
        for (int ni = 0; ni < 4; ni++) {
            union { short8 v8; s16x4 v4[2]; } u0, u1;
            u0.v4[0] = *(const s16x4*)&Vs[ni * 16 + c][quad * 8];
            u0.v4[1] = *(const s16x4*)&Vs[ni * 16 + c][quad * 8 + 4];
            u1.v4[0] = *(const s16x4*)&Vs[ni * 16 + c][32 + quad * 8];
            u1.v4[1] = *(const s16x4*)&Vs[ni * 16 + c][32 + quad * 8 + 4];
            o_acc[0][ni] = __builtin_amdgcn_mfma_f32_16x16x32_bf16(ap00, u0.v8, o_acc[0][ni], 0, 0, 0);
            o_acc[0][ni] = __builtin_amdgcn_mfma_f32_16x16x32_bf16(ap01, u1.v8, o_acc[0][ni], 0, 0, 0);
            o_acc[1][ni] = __builtin_amdgcn_mfma_f32_16x16x32_bf16(ap10, u0.v8, o_acc[1][ni], 0, 0, 0);
            o_acc[1][ni] = __builtin_amdgcn_mfma_f32_16x16x32_bf16(ap11, u1.v8, o_acc[1][ni], 0, 0, 0);
        }
        __builtin_amdgcn_s_setprio(0);
    }

    // full row-sums: quads hold disjoint kpos subsets of row c
    l0 += __shfl_xor(l0, 16);
    l0 += __shfl_xor(l0, 32);
    l1 += __shfl_xor(l1, 16);
    l1 += __shfl_xor(l1, 32);

    const size_t ybase = ((size_t)b * S) * 768 + h * 64;
#pragma unroll
    for (int r = 0; r < 4; r++) {
        const float lr0 = __shfl(l0, quad * 4 + r);
        const float lr1 = __shfl(l1, quad * 4 + r);
        const float inv0 = 1.f / fmaxf(lr0, 1e-30f);
        const float inv1 = 1.f / fmaxf(lr1, 1e-30f);
        const int srow0 = qt * 128 + w * 16 + quad * 4 + r;
        const int srow1 = srow0 + 64;
#pragma unroll
        for (int ni = 0; ni < 4; ni++) {
            Y[ybase + (size_t)srow0 * 768 + ni * 16 + c] = f2b(o_acc[0][ni][r] * inv0);
            Y[ybase + (size_t)srow1 * 768 + ni * 16 + c] = f2b(o_acc[1][ni][r] * inv1);
        }
    }
}

extern "C" void kernel_launch(void* const* d_in, const int* in_sizes, int n_in,
                              void* d_out, int out_size, void* d_ws, size_t ws_size,
                              hipStream_t stream) {
    const float* x     = (const float*)d_in[0];
    const int* attmask = (const int*)d_in[1];
    const float* Wqkv  = (const float*)d_in[2];
    const float* bqkv  = (const float*)d_in[3];
    const float* Wproj = (const float*)d_in[4];
    const float* bproj = (const float*)d_in[5];
    float* outf = (float*)d_out;

    // ws layout: bf16 staging + intermediates (all fully rewritten per launch)
    u16* base = (u16*)d_ws;
    const size_t nx = 4ull * 2048 * 768;       // 6,291,456
    const size_t nwqkv = 768ull * 2304;        // 1,769,472
    const size_t nwproj = 768ull * 768;        // 589,824
    u16* xb     = base;
    u16* Wqkvb  = xb + nx;          // TRANSPOSED: [2304][768]
    u16* Wprojb = Wqkvb + nwqkv;    // TRANSPOSED: [768][768]
    u16* Qb     = Wprojb + nwproj;
    const size_t headElems = 48ull * 2048 * 64;  // 6,291,456
    u16* Kb = Qb + headElems;
    u16* Vb = Kb + headElems;
    u16* Yb = Vb + headElems;

    // single prep launch: both weight transposes + x convert
    prep_kernel<<<1152, 256, 0, stream>>>(x, xb, Wqkv, Wqkvb, Wproj, Wprojb,
                                          (int)(nx / 8));

    // QKV GEMM: [8192,768] x [2304,768]^T + bias -> Q/K/V [b,h,s,d] bf16
    gemm_bt_kernel<0><<<dim3(18, 64), 256, 0, stream>>>(
        xb, Wqkvb, bqkv, Qb, Kb, Vb, nullptr, 8192, 2304, 768);
    // Flash attention -> Y [b,s,768] bf16 (128 q-rows per block)
    attn_kernel<<<dim3(48, 16), 256, 0, stream>>>(Qb, Kb, Vb, attmask, Yb);
    // Proj GEMM: [8192,768] x [768,768]^T + bias -> d_out fp32
    gemm_bt_kernel<1><<<dim3(6, 64), 256, 0, stream>>>(
        Yb, Wprojb, bproj, nullptr, nullptr, nullptr, outf, 8192, 768, 768);
}

// Round 9
// 235.554 us; speedup vs baseline: 1.0313x; 1.0313x over previous
//
#include <hip/hip_runtime.h>

typedef unsigned short u16;
typedef unsigned int u32;
typedef __attribute__((ext_vector_type(8))) short short8;
typedef __attribute__((ext_vector_type(4))) short s16x4;
typedef __attribute__((ext_vector_type(4))) float f32x4;

__device__ __forceinline__ float b2f(u16 u) {
    union { u32 i; float f; } v; v.i = ((u32)u) << 16; return v.f;
}
__device__ __forceinline__ u16 f2b(float f) {
    union { u32 i; float f; } v; v.f = f;
    u32 u = v.i;
    return (u16)((u + 0x7FFFu + ((u >> 16) & 1u)) >> 16);
}
__device__ __forceinline__ f32x4 zero4() {
    f32x4 v; v[0] = 0.f; v[1] = 0.f; v[2] = 0.f; v[3] = 0.f; return v;
}
// packed f32x2 -> bf16x2 (RNE); low 16 bits = first arg (HW-verified R13/R15)
__device__ __forceinline__ u32 cvtpk(float lo, float hi) {
    u32 d;
    asm("v_cvt_pk_bf16_f32 %0, %1, %2" : "=v"(d) : "v"(lo), "v"(hi));
    return d;
}
__device__ __forceinline__ float fexp2(float x) {
#if __has_builtin(__builtin_amdgcn_exp2f)
    return __builtin_amdgcn_exp2f(x);
#else
    return __expf(x * 0.6931471805599453f);
#endif
}
// async global->LDS, 16B per lane: lane l's 16B land at ldsbase + l*16.
__device__ __forceinline__ void gload16(const u16* g, u16* l) {
    __builtin_amdgcn_global_load_lds(
        (const __attribute__((address_space(1))) u32*)g,
        (__attribute__((address_space(3))) u32*)l, 16, 0, 0);
}

// ---------------------------------------------------------------------------
// Merged prep kernel (verified R18).
// blocks [0,432):   Wqkv fp32 [768][2304] -> bf16 [2304][768] transpose
// blocks [432,576): Wproj fp32 [768][768] -> bf16 [768][768] transpose
// blocks [576,1152): x fp32 -> bf16 linear convert (grid-stride)
// ---------------------------------------------------------------------------
__device__ __forceinline__ void tconv_body(const float* __restrict__ src,
                                           u16* __restrict__ dst,
                                           int K, int N, int bx, int by) {
    __shared__ u16 T[64][72];
    const int n0 = bx * 64, k0 = by * 64;
    const int tid = threadIdx.x;
    const int r = tid >> 3, cq = tid & 7;   // r: 0..31, cq: 0..7
#pragma unroll
    for (int half = 0; half < 2; half++) {
        const int k = k0 + half * 32 + r;
        const float* s = &src[(size_t)k * N + n0 + cq * 8];
        const float4 f0 = ((const float4*)s)[0];
        const float4 f1 = ((const float4*)s)[1];
        T[cq * 8 + 0][half * 32 + r] = f2b(f0.x);
        T[cq * 8 + 1][half * 32 + r] = f2b(f0.y);
        T[cq * 8 + 2][half * 32 + r] = f2b(f0.z);
        T[cq * 8 + 3][half * 32 + r] = f2b(f0.w);
        T[cq * 8 + 4][half * 32 + r] = f2b(f1.x);
        T[cq * 8 + 5][half * 32 + r] = f2b(f1.y);
        T[cq * 8 + 6][half * 32 + r] = f2b(f1.z);
        T[cq * 8 + 7][half * 32 + r] = f2b(f1.w);
    }
    __syncthreads();
#pragma unroll
    for (int half = 0; half < 2; half++) {
        const int n = half * 32 + r;
        short8 o = *(const short8*)&T[n][cq * 8];
        *(short8*)&dst[(size_t)(n0 + n) * K + k0 + cq * 8] = o;
    }
}

__global__ void prep_kernel(const float* __restrict__ x, u16* __restrict__ xb,
                            const float* __restrict__ Wqkv, u16* __restrict__ Wqkvb,
                            const float* __restrict__ Wproj, u16* __restrict__ Wprojb,
                            int n8x) {
    const int blk = blockIdx.x;
    if (blk < 432) {
        tconv_body(Wqkv, Wqkvb, 768, 2304, blk % 36, blk / 36);
    } else if (blk < 576) {
        const int id = blk - 432;
        tconv_body(Wproj, Wprojb, 768, 768, id % 12, id / 12);
    } else {
        const int stride = (1152 - 576) * 256;
        for (int i = (blk - 576) * 256 + threadIdx.x; i < n8x; i += stride) {
            const float* s = x + (size_t)i * 8;
            float4 a = ((const float4*)s)[0];
            float4 b = ((const float4*)s)[1];
            short8 o;
            o[0] = (short)f2b(a.x); o[1] = (short)f2b(a.y);
            o[2] = (short)f2b(a.z); o[3] = (short)f2b(a.w);
            o[4] = (short)f2b(b.x); o[5] = (short)f2b(b.y);
            o[6] = (short)f2b(b.z); o[7] = (short)f2b(b.w);
            ((short8*)xb)[i] = o;
        }
    }
}

// ---------------------------------------------------------------------------
// GEMM, R20 = R18's verified single-buffer BK=64 (32 KB LDS, 5 blocks/CU)
// + R19's swapped-operand epilogue ONLY.
// R19 post-mortem: double-buffer pushed LDS to 64 KB -> 2 blocks/CU; TLP loss
// beat in-wave pipelining (-15 us). Regime-gate confirmed (T3/T4 null at
// 2-phase, m230). This round isolates the epilogue half:
//   mfma(bfr, af): C per-reg index = n-dim, per-lane = m-dim -> each lane
//   holds 4 CONSECUTIVE output columns. MODE 0: 16 uint2 stores + 32 cvtpk
//   (was 64 scalar u16 + 64 f2b). MODE 1: 16 float4 stores (was 64 scalar).
//   gcb = n0+wn+ni*16+quad*4 is 4-aligned, never crosses a 768-/64-boundary.
// Chunk-parity XOR swizzle both-sides (verified R18). XCD swizzle (T1).
// ---------------------------------------------------------------------------
template <int MODE>
__global__ __launch_bounds__(256, 2) void gemm_bt_kernel(
    const u16* __restrict__ A, const u16* __restrict__ Bt,
    const float* __restrict__ bias,
    u16* __restrict__ O0, u16* __restrict__ O1, u16* __restrict__ O2,
    float* __restrict__ Of,
    int M, int N, int K)
{
    __shared__ u16 As[128 * 64];   // [m][k] linear+swizzled (gload_lds dest)
    __shared__ u16 Bs[128 * 64];   // [n][k]

    const int tid = threadIdx.x;
    const int nwgx = gridDim.x;
    const int nwg = nwgx * gridDim.y;
    int lin = blockIdx.y * nwgx + blockIdx.x;
    lin = (lin & 7) * (nwg >> 3) + (lin >> 3);   // bijective: nwg % 8 == 0
    const int m0 = (lin / nwgx) * 128, n0 = (lin % nwgx) * 128;
    const int lane = tid & 63, w = tid >> 6;
    const int quad = lane >> 4, c = lane & 15;
    const int wm = (w & 1) * 64, wn = (w >> 1) * 64;

    f32x4 acc[4][4];
#pragma unroll
    for (int i = 0; i < 4; i++)
#pragma unroll
        for (int j = 0; j < 4; j++) acc[i][j] = zero4();

    // staging: wave w covers rows [w*32, w*32+32) x 64 k per tile.
    // instr i: 8 rows (w*32+i*8+(lane>>3)), source col pre-swizzled (R18).
    const int srow = lane >> 3;                         // 0..7
    const int scol = ((lane & 7) ^ ((srow & 1) << 2)) * 8;  // pre-swizzled
    const size_t abase = (size_t)(m0 + w * 32 + srow) * K + scol;
    const size_t bbase = (size_t)(n0 + w * 32 + srow) * K + scol;
    u16* asl = &As[w * 32 * 64];   // wave-uniform LDS base
    u16* bsl = &Bs[w * 32 * 64];

    const int cpar = (c & 1) << 2;   // read-side swizzle term

    for (int k0 = 0; k0 < K; k0 += 64) {
        __syncthreads();           // previous iteration's frag reads done
#pragma unroll
        for (int i = 0; i < 4; i++)
            gload16(A + abase + (size_t)(i * 8) * K + k0, asl + i * 512);
#pragma unroll
        for (int i = 0; i < 4; i++)
            gload16(Bt + bbase + (size_t)(i * 8) * K + k0, bsl + i * 512);
        asm volatile("s_waitcnt vmcnt(0)" ::: "memory");  // tile landed in LDS
        __syncthreads();

        short8 af[4][2], bfr[4][2];
#pragma unroll
        for (int mi = 0; mi < 4; mi++)
#pragma unroll
            for (int kk = 0; kk < 2; kk++)
                af[mi][kk] = *(const short8*)
                    &As[(wm + mi * 16 + c) * 64 + (((kk * 4 + quad) ^ cpar) * 8)];
#pragma unroll
        for (int ni = 0; ni < 4; ni++)
#pragma unroll
            for (int kk = 0; kk < 2; kk++)
                bfr[ni][kk] = *(const short8*)
                    &Bs[(wn + ni * 16 + c) * 64 + (((kk * 4 + quad) ^ cpar) * 8)];
#pragma unroll
        for (int kk = 0; kk < 2; kk++)
#pragma unroll
            for (int mi = 0; mi < 4; mi++)
#pragma unroll
                for (int ni = 0; ni < 4; ni++)
                    acc[mi][ni] = __builtin_amdgcn_mfma_f32_16x16x32_bf16(
                        bfr[ni][kk], af[mi][kk], acc[mi][ni], 0, 0, 0);
    }

    // swapped-C epilogue: acc[mi][ni][r] = C[n = wn+ni*16+quad*4+r][m = wm+mi*16+c]
#pragma unroll
    for (int ni = 0; ni < 4; ni++) {
        const int gcb = n0 + wn + ni * 16 + quad * 4;   // 4 consecutive cols
        const f32x4 bv = *(const f32x4*)&bias[gcb];
        if (MODE == 0) {
            const int which = gcb / 768;                 // uniform across the 4
            const int e = gcb - which * 768;
            const int hh = e >> 6, d = e & 63;           // d..d+3, no crossing
            u16* op = (which == 0) ? O0 : (which == 1 ? O1 : O2);
#pragma unroll
            for (int mi = 0; mi < 4; mi++) {
                const int gr = m0 + wm + mi * 16 + c;    // seq row (per-lane)
                const int bb = gr >> 11, s = gr & 2047;
                uint2 pk;
                pk.x = cvtpk(acc[mi][ni][0] + bv[0], acc[mi][ni][1] + bv[1]);
                pk.y = cvtpk(acc[mi][ni][2] + bv[2], acc[mi][ni][3] + bv[3]);
                *(uint2*)&op[(((size_t)bb * 12 + hh) * 2048 + s) * 64 + d] = pk;
            }
        } else {
#pragma unroll
            for (int mi = 0; mi < 4; mi++) {
                const int gr = m0 + wm + mi * 16 + c;
                float4 o;
                o.x = acc[mi][ni][0] + bv[0];
                o.y = acc[mi][ni][1] + bv[1];
                o.z = acc[mi][ni][2] + bv[2];
                o.w = acc[mi][ni][3] + bv[3];
                *(float4*)&Of[(size_t)gr * N + gcb] = o;
            }
        }
    }
}

// ---------------------------------------------------------------------------
// Flash attention — UNCHANGED from R17/R18 (verified passing, ~90 us):
// 128 q-rows/block (2 groups/wave), swapped QK^T, cvtpk+b64 P stores,
// exp2-domain mask bias, T14 prefetch with raw barriers, T5 setprio.
// Multi-pipe saturated for this structure; frozen.
// ---------------------------------------------------------------------------
__global__ __launch_bounds__(256, 3) void attn_kernel(
    const u16* __restrict__ Q, const u16* __restrict__ Kv,
    const u16* __restrict__ Vv, const int* __restrict__ attmask,
    u16* __restrict__ Y)
{
    const int S = 2048, D = 64, NH = 12;
    __shared__ u16 Ks[64][72];          // [pos][d]
    __shared__ u16 Vs[64][68];          // [d][pos]
    __shared__ u16 Ps[4][2][16][72];    // per-wave,per-group P: [qrow][pos]
    __shared__ float msf[2048];         // exp2-domain mask bias: 0 or -43282

    const int tid = threadIdx.x;
    const int w = tid >> 6, lane = tid & 63;
    const int quad = lane >> 4, c = lane & 15;
    const int bh = blockIdx.x;        // 0..47
    const int qt = blockIdx.y;        // 0..15
    const int b = bh / NH, h = bh - b * NH;

    const u16* Qh = Q + (size_t)bh * S * D;
    const u16* Kh = Kv + (size_t)bh * S * D;
    const u16* Vh = Vv + (size_t)bh * S * D;
    const int q0 = qt * 128 + w * 16;   // group 0; group 1 at q0+64

    short8 aq00 = *(const short8*)&Qh[(size_t)(q0 + c) * D + quad * 8];
    short8 aq01 = *(const short8*)&Qh[(size_t)(q0 + c) * D + 32 + quad * 8];
    short8 aq10 = *(const short8*)&Qh[(size_t)(q0 + 64 + c) * D + quad * 8];
    short8 aq11 = *(const short8*)&Qh[(size_t)(q0 + 64 + c) * D + 32 + quad * 8];

    for (int i = tid; i < S; i += 256)
        msf[i] = (attmask[b * S + i] == 0) ? -43282.0f : 0.0f;

    f32x4 o_acc[2][4];
#pragma unroll
    for (int g = 0; g < 2; g++)
#pragma unroll
        for (int i = 0; i < 4; i++) o_acc[g][i] = zero4();
    float l0 = 0.f, l1 = 0.f;

    const int kpos = tid >> 2, kd = (tid & 3) * 8;
    const int p2 = tid >> 3, vd = (tid & 7) * 8;

    // T14 prologue: issue tile-0 loads
    short8 k0r = *(const short8*)&Kh[(size_t)kpos * D + kd];
    short8 k1r = *(const short8*)&Kh[(size_t)kpos * D + kd + 32];
    short8 v0r = *(const short8*)&Vh[(size_t)(2 * p2) * D + vd];
    short8 v1r = *(const short8*)&Vh[(size_t)(2 * p2 + 1) * D + vd];

    const float SC = 0.18033688f;  // 0.125 * log2(e)

    for (int kt = 0; kt < S / 64; kt++) {
        // ---- staging (raw barriers: vmcnt NOT drained -> prefetch in flight)
        asm volatile("" ::: "memory");
        __builtin_amdgcn_s_barrier();
        asm volatile("" ::: "memory");
        *(short8*)&Ks[kpos][kd] = k0r;
        *(short8*)&Ks[kpos][kd + 32] = k1r;
#pragma unroll
        for (int j = 0; j < 8; j++) {
            u32 pk = (u32)(u16)v0r[j] | ((u32)(u16)v1r[j] << 16);
            *(u32*)&Vs[vd + j][2 * p2] = pk;
        }
        if (kt + 1 < S / 64) {
            const int nb = (kt + 1) * 64;
            k0r = *(const short8*)&Kh[(size_t)(nb + kpos) * D + kd];
            k1r = *(const short8*)&Kh[(size_t)(nb + kpos) * D + kd + 32];
            v0r = *(const short8*)&Vh[(size_t)(nb + 2 * p2) * D + vd];
            v1r = *(const short8*)&Vh[(size_t)(nb + 2 * p2 + 1) * D + vd];
        }
        asm volatile("s_waitcnt lgkmcnt(0)" ::: "memory");
        __builtin_amdgcn_s_barrier();
        asm volatile("" ::: "memory");

        const int kbase = kt * 64;

        // ---- QK^T, swapped: s[g][ni] = S[kpos=ni*16+quad*4+r][q-group g]
        f32x4 s0[4], s1[4];
#pragma unroll
        for (int ni = 0; ni < 4; ni++) { s0[ni] = zero4(); s1[ni] = zero4(); }
        __builtin_amdgcn_s_setprio(1);
#pragma unroll
        for (int ni = 0; ni < 4; ni++) {
            short8 bk0 = *(const short8*)&Ks[ni * 16 + c][quad * 8];
            short8 bk1 = *(const short8*)&Ks[ni * 16 + c][32 + quad * 8];
            s0[ni] = __builtin_amdgcn_mfma_f32_16x16x32_bf16(bk0, aq00, s0[ni], 0, 0, 0);
            s0[ni] = __builtin_amdgcn_mfma_f32_16x16x32_bf16(bk1, aq01, s0[ni], 0, 0, 0);
            s1[ni] = __builtin_amdgcn_mfma_f32_16x16x32_bf16(bk0, aq10, s1[ni], 0, 0, 0);
            s1[ni] = __builtin_amdgcn_mfma_f32_16x16x32_bf16(bk1, aq11, s1[ni], 0, 0, 0);
        }
        __builtin_amdgcn_s_setprio(0);

        // ---- softmax per group: cvtpk pairs + one b64 store per (g,ni) ----
#pragma unroll
        for (int ni = 0; ni < 4; ni++) {
            const f32x4 bias = *(const f32x4*)&msf[kbase + ni * 16 + quad * 4];
            {
                float p0 = fexp2(fmaf(s0[ni][0], SC, bias[0]));
                float p1 = fexp2(fmaf(s0[ni][1], SC, bias[1]));
                float p2f = fexp2(fmaf(s0[ni][2], SC, bias[2]));
                float p3 = fexp2(fmaf(s0[ni][3], SC, bias[3]));
                l0 += (p0 + p1) + (p2f + p3);
                uint2 pk;
                pk.x = cvtpk(p0, p1);
                pk.y = cvtpk(p2f, p3);
                *(uint2*)&Ps[w][0][c][ni * 16 + quad * 4] = pk;
            }
            {
                float p0 = fexp2(fmaf(s1[ni][0], SC, bias[0]));
                float p1 = fexp2(fmaf(s1[ni][1], SC, bias[1]));
                float p2f = fexp2(fmaf(s1[ni][2], SC, bias[2]));
                float p3 = fexp2(fmaf(s1[ni][3], SC, bias[3]));
                l1 += (p0 + p1) + (p2f + p3);
                uint2 pk;
                pk.x = cvtpk(p0, p1);
                pk.y = cvtpk(p2f, p3);
                *(uint2*)&Ps[w][1][c][ni * 16 + quad * 4] = pk;
            }
        }
        // Ps is per-wave: in-order DS pipeline orders stores before our reads.

        short8 ap00 = *(const short8*)&Ps[w][0][c][quad * 8];
        short8 ap01 = *(const short8*)&Ps[w][0][c][32 + quad * 8];
        short8 ap10 = *(const short8*)&Ps[w][1][c][quad * 8];
        short8 ap11 = *(const short8*)&Ps[w][1][c][32 + quad * 8];
        __builtin_amdgcn_s_setprio(1);
#pragma unroll
        for (int ni = 0; ni < 4; ni++) {
            union { short8 v8; s16x4 v4[2]; } u0, u1;
            u0.v4[0] = *(const s16x4*)&Vs[ni * 16 + c][quad * 8];
            u0.v4[1] = *(const s16x4*)&Vs[ni * 16 + c][quad * 8 + 4];
            u1.v4[0] = *(const s16x4*)&Vs[ni * 16 + c][32 + quad * 8];
            u1.v4[1] = *(const s16x4*)&Vs[ni * 16 + c][32 + quad * 8 + 4];
            o_acc[0][ni] = __builtin_amdgcn_mfma_f32_16x16x32_bf16(ap00, u0.v8, o_acc[0][ni], 0, 0, 0);
            o_acc[0][ni] = __builtin_amdgcn_mfma_f32_16x16x32_bf16(ap01, u1.v8, o_acc[0][ni], 0, 0, 0);
            o_acc[1][ni] = __builtin_amdgcn_mfma_f32_16x16x32_bf16(ap10, u0.v8, o_acc[1][ni], 0, 0, 0);
            o_acc[1][ni] = __builtin_amdgcn_mfma_f32_16x16x32_bf16(ap11, u1.v8, o_acc[1][ni], 0, 0, 0);
        }
        __builtin_amdgcn_s_setprio(0);
    }

    // full row-sums: quads hold disjoint kpos subsets of row c
    l0 += __shfl_xor(l0, 16);
    l0 += __shfl_xor(l0, 32);
    l1 += __shfl_xor(l1, 16);
    l1 += __shfl_xor(l1, 32);

    const size_t ybase = ((size_t)b * S) * 768 + h * 64;
#pragma unroll
    for (int r = 0; r < 4; r++) {
        const float lr0 = __shfl(l0, quad * 4 + r);
        const float lr1 = __shfl(l1, quad * 4 + r);
        const float inv0 = 1.f / fmaxf(lr0, 1e-30f);
        const float inv1 = 1.f / fmaxf(lr1, 1e-30f);
        const int srow0 = qt * 128 + w * 16 + quad * 4 + r;
        const int srow1 = srow0 + 64;
#pragma unroll
        for (int ni = 0; ni < 4; ni++) {
            Y[ybase + (size_t)srow0 * 768 + ni * 16 + c] = f2b(o_acc[0][ni][r] * inv0);
            Y[ybase + (size_t)srow1 * 768 + ni * 16 + c] = f2b(o_acc[1][ni][r] * inv1);
        }
    }
}

extern "C" void kernel_launch(void* const* d_in, const int* in_sizes, int n_in,
                              void* d_out, int out_size, void* d_ws, size_t ws_size,
                              hipStream_t stream) {
    const float* x     = (const float*)d_in[0];
    const int* attmask = (const int*)d_in[1];
    const float* Wqkv  = (const float*)d_in[2];
    const float* bqkv  = (const float*)d_in[3];
    const float* Wproj = (const float*)d_in[4];
    const float* bproj = (const float*)d_in[5];
    float* outf = (float*)d_out;

    // ws layout: bf16 staging + intermediates (all fully rewritten per launch)
    u16* base = (u16*)d_ws;
    const size_t nx = 4ull * 2048 * 768;       // 6,291,456
    const size_t nwqkv = 768ull * 2304;        // 1,769,472
    const size_t nwproj = 768ull * 768;        // 589,824
    u16* xb     = base;
    u16* Wqkvb  = xb + nx;          // TRANSPOSED: [2304][768]
    u16* Wprojb = Wqkvb + nwqkv;    // TRANSPOSED: [768][768]
    u16* Qb     = Wprojb + nwproj;
    const size_t headElems = 48ull * 2048 * 64;  // 6,291,456
    u16* Kb = Qb + headElems;
    u16* Vb = Kb + headElems;
    u16* Yb = Vb + headElems;

    // single prep launch: both weight transposes + x convert
    prep_kernel<<<1152, 256, 0, stream>>>(x, xb, Wqkv, Wqkvb, Wproj, Wprojb,
                                          (int)(nx / 8));

    // QKV GEMM: [8192,768] x [2304,768]^T + bias -> Q/K/V [b,h,s,d] bf16
    gemm_bt_kernel<0><<<dim3(18, 64), 256, 0, stream>>>(
        xb, Wqkvb, bqkv, Qb, Kb, Vb, nullptr, 8192, 2304, 768);
    // Flash attention -> Y [b,s,768] bf16 (128 q-rows per block)
    attn_kernel<<<dim3(48, 16), 256, 0, stream>>>(Qb, Kb, Vb, attmask, Yb);
    // Proj GEMM: [8192,768] x [768,768]^T + bias -> d_out fp32
    gemm_bt_kernel<1><<<dim3(6, 64), 256, 0, stream>>>(
        Yb, Wprojb, bproj, nullptr, nullptr, nullptr, outf, 8192, 768, 768);
}

// Round 11
// 230.948 us; speedup vs baseline: 1.0519x; 1.0199x over previous
//
#include <hip/hip_runtime.h>

typedef unsigned short u16;
typedef unsigned int u32;
typedef __attribute__((ext_vector_type(8))) short short8;
typedef __attribute__((ext_vector_type(4))) short s16x4;
typedef __attribute__((ext_vector_type(4))) float f32x4;

__device__ __forceinline__ float b2f(u16 u) {
    union { u32 i; float f; } v; v.i = ((u32)u) << 16; return v.f;
}
__device__ __forceinline__ u16 f2b(float f) {
    union { u32 i; float f; } v; v.f = f;
    u32 u = v.i;
    return (u16)((u + 0x7FFFu + ((u >> 16) & 1u)) >> 16);
}
__device__ __forceinline__ f32x4 zero4() {
    f32x4 v; v[0] = 0.f; v[1] = 0.f; v[2] = 0.f; v[3] = 0.f; return v;
}
// packed f32x2 -> bf16x2 (RNE); low 16 bits = first arg (HW-verified R13/R15)
__device__ __forceinline__ u32 cvtpk(float lo, float hi) {
    u32 d;
    asm("v_cvt_pk_bf16_f32 %0, %1, %2" : "=v"(d) : "v"(lo), "v"(hi));
    return d;
}
__device__ __forceinline__ float fexp2(float x) {
#if __has_builtin(__builtin_amdgcn_exp2f)
    return __builtin_amdgcn_exp2f(x);
#else
    return __expf(x * 0.6931471805599453f);
#endif
}
// async global->LDS, 16B per lane: lane l's 16B land at ldsbase + l*16.
__device__ __forceinline__ void gload16(const u16* g, u16* l) {
    __builtin_amdgcn_global_load_lds(
        (const __attribute__((address_space(1))) u32*)g,
        (__attribute__((address_space(3))) u32*)l, 16, 0, 0);
}

// ---------------------------------------------------------------------------
// Merged prep kernel (verified R18).
// blocks [0,432):   Wqkv fp32 [768][2304] -> bf16 [2304][768] transpose
// blocks [432,576): Wproj fp32 [768][768] -> bf16 [768][768] transpose
// blocks [576,1152): x fp32 -> bf16 linear convert (grid-stride)
// ---------------------------------------------------------------------------
__device__ __forceinline__ void tconv_body(const float* __restrict__ src,
                                           u16* __restrict__ dst,
                                           int K, int N, int bx, int by) {
    __shared__ u16 T[64][72];
    const int n0 = bx * 64, k0 = by * 64;
    const int tid = threadIdx.x;
    const int r = tid >> 3, cq = tid & 7;   // r: 0..31, cq: 0..7
#pragma unroll
    for (int half = 0; half < 2; half++) {
        const int k = k0 + half * 32 + r;
        const float* s = &src[(size_t)k * N + n0 + cq * 8];
        const float4 f0 = ((const float4*)s)[0];
        const float4 f1 = ((const float4*)s)[1];
        T[cq * 8 + 0][half * 32 + r] = f2b(f0.x);
        T[cq * 8 + 1][half * 32 + r] = f2b(f0.y);
        T[cq * 8 + 2][half * 32 + r] = f2b(f0.z);
        T[cq * 8 + 3][half * 32 + r] = f2b(f0.w);
        T[cq * 8 + 4][half * 32 + r] = f2b(f1.x);
        T[cq * 8 + 5][half * 32 + r] = f2b(f1.y);
        T[cq * 8 + 6][half * 32 + r] = f2b(f1.z);
        T[cq * 8 + 7][half * 32 + r] = f2b(f1.w);
    }
    __syncthreads();
#pragma unroll
    for (int half = 0; half < 2; half++) {
        const int n = half * 32 + r;
        short8 o = *(const short8*)&T[n][cq * 8];
        *(short8*)&dst[(size_t)(n0 + n) * K + k0 + cq * 8] = o;
    }
}

__global__ void prep_kernel(const float* __restrict__ x, u16* __restrict__ xb,
                            const float* __restrict__ Wqkv, u16* __restrict__ Wqkvb,
                            const float* __restrict__ Wproj, u16* __restrict__ Wprojb,
                            int n8x) {
    const int blk = blockIdx.x;
    if (blk < 432) {
        tconv_body(Wqkv, Wqkvb, 768, 2304, blk % 36, blk / 36);
    } else if (blk < 576) {
        const int id = blk - 432;
        tconv_body(Wproj, Wprojb, 768, 768, id % 12, id / 12);
    } else {
        const int stride = (1152 - 576) * 256;
        for (int i = (blk - 576) * 256 + threadIdx.x; i < n8x; i += stride) {
            const float* s = x + (size_t)i * 8;
            float4 a = ((const float4*)s)[0];
            float4 b = ((const float4*)s)[1];
            short8 o;
            o[0] = (short)f2b(a.x); o[1] = (short)f2b(a.y);
            o[2] = (short)f2b(a.z); o[3] = (short)f2b(a.w);
            o[4] = (short)f2b(b.x); o[5] = (short)f2b(b.y);
            o[6] = (short)f2b(b.z); o[7] = (short)f2b(b.w);
            ((short8*)xb)[i] = o;
        }
    }
}

// ---------------------------------------------------------------------------
// GEMM — R18 VERBATIM (verified best). BK=64, single buffer, chunk-parity
// XOR swizzle both-sides, 32 KB LDS, scalar cross-lane-coalesced epilogue.
// MODE 0: scatter bf16 into Q/K/V. MODE 1: fp32 out. XCD swizzle (T1).
// ---------------------------------------------------------------------------
template <int MODE>
__global__ __launch_bounds__(256, 2) void gemm_bt_kernel(
    const u16* __restrict__ A, const u16* __restrict__ Bt,
    const float* __restrict__ bias,
    u16* __restrict__ O0, u16* __restrict__ O1, u16* __restrict__ O2,
    float* __restrict__ Of,
    int M, int N, int K)
{
    __shared__ u16 As[128 * 64];   // [m][k] linear+swizzled (gload_lds dest)
    __shared__ u16 Bs[128 * 64];   // [n][k]

    const int tid = threadIdx.x;
    const int nwgx = gridDim.x;
    const int nwg = nwgx * gridDim.y;
    int lin = blockIdx.y * nwgx + blockIdx.x;
    lin = (lin & 7) * (nwg >> 3) + (lin >> 3);   // bijective: nwg % 8 == 0
    const int m0 = (lin / nwgx) * 128, n0 = (lin % nwgx) * 128;
    const int lane = tid & 63, w = tid >> 6;
    const int quad = lane >> 4, c = lane & 15;
    const int wm = (w & 1) * 64, wn = (w >> 1) * 64;

    f32x4 acc[4][4];
#pragma unroll
    for (int i = 0; i < 4; i++)
#pragma unroll
        for (int j = 0; j < 4; j++) acc[i][j] = zero4();

    // staging: wave w covers rows [w*32, w*32+32) x 64 k per tile.
    // instr i: 8 rows (w*32+i*8+(lane>>3)), source col pre-swizzled (R18).
    const int srow = lane >> 3;                         // 0..7
    const int scol = ((lane & 7) ^ ((srow & 1) << 2)) * 8;  // pre-swizzled
    const size_t abase = (size_t)(m0 + w * 32 + srow) * K + scol;
    const size_t bbase = (size_t)(n0 + w * 32 + srow) * K + scol;
    u16* asl = &As[w * 32 * 64];   // wave-uniform LDS base
    u16* bsl = &Bs[w * 32 * 64];

    const int cpar = (c & 1) << 2;   // read-side swizzle term

    for (int k0 = 0; k0 < K; k0 += 64) {
        __syncthreads();           // previous iteration's frag reads done
#pragma unroll
        for (int i = 0; i < 4; i++)
            gload16(A + abase + (size_t)(i * 8) * K + k0, asl + i * 512);
#pragma unroll
        for (int i = 0; i < 4; i++)
            gload16(Bt + bbase + (size_t)(i * 8) * K + k0, bsl + i * 512);
        asm volatile("s_waitcnt vmcnt(0)" ::: "memory");  // tile landed in LDS
        __syncthreads();

        short8 af[4][2], bfr[4][2];
#pragma unroll
        for (int mi = 0; mi < 4; mi++)
#pragma unroll
            for (int kk = 0; kk < 2; kk++)
                af[mi][kk] = *(const short8*)
                    &As[(wm + mi * 16 + c) * 64 + (((kk * 4 + quad) ^ cpar) * 8)];
#pragma unroll
        for (int ni = 0; ni < 4; ni++)
#pragma unroll
            for (int kk = 0; kk < 2; kk++)
                bfr[ni][kk] = *(const short8*)
                    &Bs[(wn + ni * 16 + c) * 64 + (((kk * 4 + quad) ^ cpar) * 8)];
#pragma unroll
        for (int kk = 0; kk < 2; kk++)
#pragma unroll
            for (int mi = 0; mi < 4; mi++)
#pragma unroll
                for (int ni = 0; ni < 4; ni++)
                    acc[mi][ni] = __builtin_amdgcn_mfma_f32_16x16x32_bf16(
                        af[mi][kk], bfr[ni][kk], acc[mi][ni], 0, 0, 0);
    }

#pragma unroll
    for (int ni = 0; ni < 4; ni++) {
        const int gc = n0 + wn + ni * 16 + c;
        const float bv = bias[gc];
        if (MODE == 0) {
            const int which = gc / 768;
            const int e = gc - which * 768;
            const int hh = e >> 6, d = e & 63;
            u16* op = (which == 0) ? O0 : (which == 1 ? O1 : O2);
#pragma unroll
            for (int mi = 0; mi < 4; mi++)
#pragma unroll
                for (int r = 0; r < 4; r++) {
                    const int gr = m0 + wm + mi * 16 + quad * 4 + r;
                    const int bb = gr >> 11, s = gr & 2047;
                    op[(((size_t)bb * 12 + hh) * 2048 + s) * 64 + d] =
                        f2b(acc[mi][ni][r] + bv);
                }
        } else {
#pragma unroll
            for (int mi = 0; mi < 4; mi++)
#pragma unroll
                for (int r = 0; r < 4; r++) {
                    const int gr = m0 + wm + mi * 16 + quad * 4 + r;
                    Of[(size_t)gr * N + gc] = acc[mi][ni][r] + bv;
                }
        }
    }
}

// ---------------------------------------------------------------------------
// Flash attention, R22: occupancy lever, alignment-safe form.
// R21 failed on Ps stride 72->68: row stride 136 B is not 16B-multiple ->
// misaligned ds_read_b128 on odd rows (absmax 0.13). Fix: Ps stride stays 72
// (all P addresses byte-identical to verified R17); the msb bf16 mask alone
// gets LDS to 40448 B -> 4 blocks/CU (4 x 40448 = 161792 <= 163840; even at
// 1 KiB rounding, 40960 x 4 = exactly 160 KiB).
//   - msb bf16[2048]: bias 0xC700 = -32768; expand via shift/and (4 VALU per
//     ni shared across groups); exp2(-32768+s) == 0 exactly (masked).
//   - launch_bounds(256,4); everything else R17-verbatim (verified ~90 us).
// ---------------------------------------------------------------------------
__global__ __launch_bounds__(256, 4) void attn_kernel(
    const u16* __restrict__ Q, const u16* __restrict__ Kv,
    const u16* __restrict__ Vv, const int* __restrict__ attmask,
    u16* __restrict__ Y)
{
    const int S = 2048, D = 64, NH = 12;
    __shared__ u16 Ks[64][72];          // [pos][d]
    __shared__ u16 Vs[64][68];          // [d][pos]
    __shared__ u16 Ps[4][2][16][72];    // per-wave,per-group P: [qrow][pos]
    __shared__ u16 msb[2048];           // bf16 exp2-domain bias: 0 or -32768

    const int tid = threadIdx.x;
    const int w = tid >> 6, lane = tid & 63;
    const int quad = lane >> 4, c = lane & 15;
    const int bh = blockIdx.x;        // 0..47
    const int qt = blockIdx.y;        // 0..15
    const int b = bh / NH, h = bh - b * NH;

    const u16* Qh = Q + (size_t)bh * S * D;
    const u16* Kh = Kv + (size_t)bh * S * D;
    const u16* Vh = Vv + (size_t)bh * S * D;
    const int q0 = qt * 128 + w * 16;   // group 0; group 1 at q0+64

    short8 aq00 = *(const short8*)&Qh[(size_t)(q0 + c) * D + quad * 8];
    short8 aq01 = *(const short8*)&Qh[(size_t)(q0 + c) * D + 32 + quad * 8];
    short8 aq10 = *(const short8*)&Qh[(size_t)(q0 + 64 + c) * D + quad * 8];
    short8 aq11 = *(const short8*)&Qh[(size_t)(q0 + 64 + c) * D + 32 + quad * 8];

    // whole-sequence mask bias, bf16: 0xC700 = -32768 (exp2 -> exact 0)
    for (int i = tid; i < S; i += 256)
        msb[i] = (attmask[b * S + i] == 0) ? (u16)0xC700 : (u16)0;

    f32x4 o_acc[2][4];
#pragma unroll
    for (int g = 0; g < 2; g++)
#pragma unroll
        for (int i = 0; i < 4; i++) o_acc[g][i] = zero4();
    float l0 = 0.f, l1 = 0.f;

    const int kpos = tid >> 2, kd = (tid & 3) * 8;
    const int p2 = tid >> 3, vd = (tid & 7) * 8;

    // T14 prologue: issue tile-0 loads
    short8 k0r = *(const short8*)&Kh[(size_t)kpos * D + kd];
    short8 k1r = *(const short8*)&Kh[(size_t)kpos * D + kd + 32];
    short8 v0r = *(const short8*)&Vh[(size_t)(2 * p2) * D + vd];
    short8 v1r = *(const short8*)&Vh[(size_t)(2 * p2 + 1) * D + vd];

    const float SC = 0.18033688f;  // 0.125 * log2(e)

    for (int kt = 0; kt < S / 64; kt++) {
        // ---- staging (raw barriers: vmcnt NOT drained -> prefetch in flight)
        asm volatile("" ::: "memory");
        __builtin_amdgcn_s_barrier();
        asm volatile("" ::: "memory");
        *(short8*)&Ks[kpos][kd] = k0r;
        *(short8*)&Ks[kpos][kd + 32] = k1r;
#pragma unroll
        for (int j = 0; j < 8; j++) {
            u32 pk = (u32)(u16)v0r[j] | ((u32)(u16)v1r[j] << 16);
            *(u32*)&Vs[vd + j][2 * p2] = pk;
        }
        if (kt + 1 < S / 64) {
            const int nb = (kt + 1) * 64;
            k0r = *(const short8*)&Kh[(size_t)(nb + kpos) * D + kd];
            k1r = *(const short8*)&Kh[(size_t)(nb + kpos) * D + kd + 32];
            v0r = *(const short8*)&Vh[(size_t)(nb + 2 * p2) * D + vd];
            v1r = *(const short8*)&Vh[(size_t)(nb + 2 * p2 + 1) * D + vd];
        }
        asm volatile("s_waitcnt lgkmcnt(0)" ::: "memory");
        __builtin_amdgcn_s_barrier();
        asm volatile("" ::: "memory");

        const int kbase = kt * 64;

        // ---- QK^T, swapped: s[g][ni] = S[kpos=ni*16+quad*4+r][q-group g]
        f32x4 s0[4], s1[4];
#pragma unroll
        for (int ni = 0; ni < 4; ni++) { s0[ni] = zero4(); s1[ni] = zero4(); }
        __builtin_amdgcn_s_setprio(1);
#pragma unroll
        for (int ni = 0; ni < 4; ni++) {
            short8 bk0 = *(const short8*)&Ks[ni * 16 + c][quad * 8];
            short8 bk1 = *(const short8*)&Ks[ni * 16 + c][32 + quad * 8];
            s0[ni] = __builtin_amdgcn_mfma_f32_16x16x32_bf16(bk0, aq00, s0[ni], 0, 0, 0);
            s0[ni] = __builtin_amdgcn_mfma_f32_16x16x32_bf16(bk1, aq01, s0[ni], 0, 0, 0);
            s1[ni] = __builtin_amdgcn_mfma_f32_16x16x32_bf16(bk0, aq10, s1[ni], 0, 0, 0);
            s1[ni] = __builtin_amdgcn_mfma_f32_16x16x32_bf16(bk1, aq11, s1[ni], 0, 0, 0);
        }
        __builtin_amdgcn_s_setprio(0);

        // ---- softmax per group: bf16 bias expand + cvtpk + b64 stores ----
#pragma unroll
        for (int ni = 0; ni < 4; ni++) {
            const uint2 mb = *(const uint2*)&msb[kbase + ni * 16 + quad * 4];
            union { u32 i; float f; } e0, e1, e2, e3;
            e0.i = mb.x << 16; e1.i = mb.x & 0xffff0000u;
            e2.i = mb.y << 16; e3.i = mb.y & 0xffff0000u;
            {
                float p0 = fexp2(fmaf(s0[ni][0], SC, e0.f));
                float p1 = fexp2(fmaf(s0[ni][1], SC, e1.f));
                float p2f = fexp2(fmaf(s0[ni][2], SC, e2.f));
                float p3 = fexp2(fmaf(s0[ni][3], SC, e3.f));
                l0 += (p0 + p1) + (p2f + p3);
                uint2 pk;
                pk.x = cvtpk(p0, p1);
                pk.y = cvtpk(p2f, p3);
                *(uint2*)&Ps[w][0][c][ni * 16 + quad * 4] = pk;
            }
            {
                float p0 = fexp2(fmaf(s1[ni][0], SC, e0.f));
                float p1 = fexp2(fmaf(s1[ni][1], SC, e1.f));
                float p2f = fexp2(fmaf(s1[ni][2], SC, e2.f));
                float p3 = fexp2(fmaf(s1[ni][3], SC, e3.f));
                l1 += (p0 + p1) + (p2f + p3);
                uint2 pk;
                pk.x = cvtpk(p0, p1);
                pk.y = cvtpk(p2f, p3);
                *(uint2*)&Ps[w][1][c][ni * 16 + quad * 4] = pk;
            }
        }
        // Ps is per-wave: in-order DS pipeline orders stores before our reads.

        short8 ap00 = *(const short8*)&Ps[w][0][c][quad * 8];
        short8 ap01 = *(const short8*)&Ps[w][0][c][32 + quad * 8];
        short8 ap10 = *(const short8*)&Ps[w][1][c][quad * 8];
        short8 ap11 = *(const short8*)&Ps[w][1][c][32 + quad * 8];
        __builtin_amdgcn_s_setprio(1);
#pragma unroll
        for (int ni = 0; ni < 4; ni++) {
            union { short8 v8; s16x4 v4[2]; } u0, u1;
            u0.v4[0] = *(const s16x4*)&Vs[ni * 16 + c][quad * 8];
            u0.v4[1] = *(const s16x4*)&Vs[ni * 16 + c][quad * 8 + 4];
            u1.v4[0] = *(const s16x4*)&Vs[ni * 16 + c][32 + quad * 8];
            u1.v4[1] = *(const s16x4*)&Vs[ni * 16 + c][32 + quad * 8 + 4];
            o_acc[0][ni] = __builtin_amdgcn_mfma_f32_16x16x32_bf16(ap00, u0.v8, o_acc[0][ni], 0, 0, 0);
            o_acc[0][ni] = __builtin_amdgcn_mfma_f32_16x16x32_bf16(ap01, u1.v8, o_acc[0][ni], 0, 0, 0);
            o_acc[1][ni] = __builtin_amdgcn_mfma_f32_16x16x32_bf16(ap10, u0.v8, o_acc[1][ni], 0, 0, 0);
            o_acc[1][ni] = __builtin_amdgcn_mfma_f32_16x16x32_bf16(ap11, u1.v8, o_acc[1][ni], 0, 0, 0);
        }
        __builtin_amdgcn_s_setprio(0);
    }

    // full row-sums: quads hold disjoint kpos subsets of row c
    l0 += __shfl_xor(l0, 16);
    l0 += __shfl_xor(l0, 32);
    l1 += __shfl_xor(l1, 16);
    l1 += __shfl_xor(l1, 32);

    const size_t ybase = ((size_t)b * S) * 768 + h * 64;
#pragma unroll
    for (int r = 0; r < 4; r++) {
        const float lr0 = __shfl(l0, quad * 4 + r);
        const float lr1 = __shfl(l1, quad * 4 + r);
        const float inv0 = 1.f / fmaxf(lr0, 1e-30f);
        const float inv1 = 1.f / fmaxf(lr1, 1e-30f);
        const int srow0 = qt * 128 + w * 16 + quad * 4 + r;
        const int srow1 = srow0 + 64;
#pragma unroll
        for (int ni = 0; ni < 4; ni++) {
            Y[ybase + (size_t)srow0 * 768 + ni * 16 + c] = f2b(o_acc[0][ni][r] * inv0);
            Y[ybase + (size_t)srow1 * 768 + ni * 16 + c] = f2b(o_acc[1][ni][r] * inv1);
        }
    }
}

extern "C" void kernel_launch(void* const* d_in, const int* in_sizes, int n_in,
                              void* d_out, int out_size, void* d_ws, size_t ws_size,
                              hipStream_t stream) {
    const float* x     = (const float*)d_in[0];
    const int* attmask = (const int*)d_in[1];
    const float* Wqkv  = (const float*)d_in[2];
    const float* bqkv  = (const float*)d_in[3];
    const float* Wproj = (const float*)d_in[4];
    const float* bproj = (const float*)d_in[5];
    float* outf = (float*)d_out;

    // ws layout: bf16 staging + intermediates (all fully rewritten per launch)
    u16* base = (u16*)d_ws;
    const size_t nx = 4ull * 2048 * 768;       // 6,291,456
    const size_t nwqkv = 768ull * 2304;        // 1,769,472
    const size_t nwproj = 768ull * 768;        // 589,824
    u16* xb     = base;
    u16* Wqkvb  = xb + nx;          // TRANSPOSED: [2304][768]
    u16* Wprojb = Wqkvb + nwqkv;    // TRANSPOSED: [768][768]
    u16* Qb     = Wprojb + nwproj;
    const size_t headElems = 48ull * 2048 * 64;  // 6,291,456
    u16* Kb = Qb + headElems;
    u16* Vb = Kb + headElems;
    u16* Yb = Vb + headElems;

    // single prep launch: both weight transposes + x convert
    prep_kernel<<<1152, 256, 0, stream>>>(x, xb, Wqkv, Wqkvb, Wproj, Wprojb,
                                          (int)(nx / 8));

    // QKV GEMM: [8192,768] x [2304,768]^T + bias -> Q/K/V [b,h,s,d] bf16
    gemm_bt_kernel<0><<<dim3(18, 64), 256, 0, stream>>>(
        xb, Wqkvb, bqkv, Qb, Kb, Vb, nullptr, 8192, 2304, 768);
    // Flash attention -> Y [b,s,768] bf16 (128 q-rows per block)
    attn_kernel<<<dim3(48, 16), 256, 0, stream>>>(Qb, Kb, Vb, attmask, Yb);
    // Proj GEMM: [8192,768] x [768,768]^T + bias -> d_out fp32
    gemm_bt_kernel<1><<<dim3(6, 64), 256, 0, stream>>>(
        Yb, Wprojb, bproj, nullptr, nullptr, nullptr, outf, 8192, 768, 768);
}

// Round 12
// 224.872 us; speedup vs baseline: 1.0803x; 1.0270x over previous
//
#include <hip/hip_runtime.h>

typedef unsigned short u16;
typedef unsigned int u32;
typedef __attribute__((ext_vector_type(8))) short short8;
typedef __attribute__((ext_vector_type(4))) short s16x4;
typedef __attribute__((ext_vector_type(4))) float f32x4;

__device__ __forceinline__ float b2f(u16 u) {
    union { u32 i; float f; } v; v.i = ((u32)u) << 16; return v.f;
}
__device__ __forceinline__ u16 f2b(float f) {
    union { u32 i; float f; } v; v.f = f;
    u32 u = v.i;
    return (u16)((u + 0x7FFFu + ((u >> 16) & 1u)) >> 16);
}
__device__ __forceinline__ f32x4 zero4() {
    f32x4 v; v[0] = 0.f; v[1] = 0.f; v[2] = 0.f; v[3] = 0.f; return v;
}
// packed f32x2 -> bf16x2 (RNE); low 16 bits = first arg (HW-verified R13/R15)
__device__ __forceinline__ u32 cvtpk(float lo, float hi) {
    u32 d;
    asm("v_cvt_pk_bf16_f32 %0, %1, %2" : "=v"(d) : "v"(lo), "v"(hi));
    return d;
}
__device__ __forceinline__ float fexp2(float x) {
#if __has_builtin(__builtin_amdgcn_exp2f)
    return __builtin_amdgcn_exp2f(x);
#else
    return __expf(x * 0.6931471805599453f);
#endif
}
// async global->LDS, 16B per lane: lane l's 16B land at ldsbase + l*16.
__device__ __forceinline__ void gload16(const u16* g, u16* l) {
    __builtin_amdgcn_global_load_lds(
        (const __attribute__((address_space(1))) u32*)g,
        (__attribute__((address_space(3))) u32*)l, 16, 0, 0);
}

// ---------------------------------------------------------------------------
// Merged prep kernel (verified R18).
// blocks [0,432):   Wqkv fp32 [768][2304] -> bf16 [2304][768] transpose
// blocks [432,576): Wproj fp32 [768][768] -> bf16 [768][768] transpose
// blocks [576,1152): x fp32 -> bf16 linear convert (grid-stride)
// ---------------------------------------------------------------------------
__device__ __forceinline__ void tconv_body(const float* __restrict__ src,
                                           u16* __restrict__ dst,
                                           int K, int N, int bx, int by) {
    __shared__ u16 T[64][72];
    const int n0 = bx * 64, k0 = by * 64;
    const int tid = threadIdx.x;
    const int r = tid >> 3, cq = tid & 7;   // r: 0..31, cq: 0..7
#pragma unroll
    for (int half = 0; half < 2; half++) {
        const int k = k0 + half * 32 + r;
        const float* s = &src[(size_t)k * N + n0 + cq * 8];
        const float4 f0 = ((const float4*)s)[0];
        const float4 f1 = ((const float4*)s)[1];
        T[cq * 8 + 0][half * 32 + r] = f2b(f0.x);
        T[cq * 8 + 1][half * 32 + r] = f2b(f0.y);
        T[cq * 8 + 2][half * 32 + r] = f2b(f0.z);
        T[cq * 8 + 3][half * 32 + r] = f2b(f0.w);
        T[cq * 8 + 4][half * 32 + r] = f2b(f1.x);
        T[cq * 8 + 5][half * 32 + r] = f2b(f1.y);
        T[cq * 8 + 6][half * 32 + r] = f2b(f1.z);
        T[cq * 8 + 7][half * 32 + r] = f2b(f1.w);
    }
    __syncthreads();
#pragma unroll
    for (int half = 0; half < 2; half++) {
        const int n = half * 32 + r;
        short8 o = *(const short8*)&T[n][cq * 8];
        *(short8*)&dst[(size_t)(n0 + n) * K + k0 + cq * 8] = o;
    }
}

__global__ void prep_kernel(const float* __restrict__ x, u16* __restrict__ xb,
                            const float* __restrict__ Wqkv, u16* __restrict__ Wqkvb,
                            const float* __restrict__ Wproj, u16* __restrict__ Wprojb,
                            int n8x) {
    const int blk = blockIdx.x;
    if (blk < 432) {
        tconv_body(Wqkv, Wqkvb, 768, 2304, blk % 36, blk / 36);
    } else if (blk < 576) {
        const int id = blk - 432;
        tconv_body(Wproj, Wprojb, 768, 768, id % 12, id / 12);
    } else {
        const int stride = (1152 - 576) * 256;
        for (int i = (blk - 576) * 256 + threadIdx.x; i < n8x; i += stride) {
            const float* s = x + (size_t)i * 8;
            float4 a = ((const float4*)s)[0];
            float4 b = ((const float4*)s)[1];
            short8 o;
            o[0] = (short)f2b(a.x); o[1] = (short)f2b(a.y);
            o[2] = (short)f2b(a.z); o[3] = (short)f2b(a.w);
            o[4] = (short)f2b(b.x); o[5] = (short)f2b(b.y);
            o[6] = (short)f2b(b.z); o[7] = (short)f2b(b.w);
            ((short8*)xb)[i] = o;
        }
    }
}

// ---------------------------------------------------------------------------
// GEMM — R18 VERBATIM (verified best). BK=64, single buffer, chunk-parity
// XOR swizzle both-sides, 32 KB LDS, scalar cross-lane-coalesced epilogue.
// MODE 0: scatter bf16 into Q/K/V. MODE 1: fp32 out. XCD swizzle (T1).
// ---------------------------------------------------------------------------
template <int MODE>
__global__ __launch_bounds__(256, 2) void gemm_bt_kernel(
    const u16* __restrict__ A, const u16* __restrict__ Bt,
    const float* __restrict__ bias,
    u16* __restrict__ O0, u16* __restrict__ O1, u16* __restrict__ O2,
    float* __restrict__ Of,
    int M, int N, int K)
{
    __shared__ u16 As[128 * 64];   // [m][k] linear+swizzled (gload_lds dest)
    __shared__ u16 Bs[128 * 64];   // [n][k]

    const int tid = threadIdx.x;
    const int nwgx = gridDim.x;
    const int nwg = nwgx * gridDim.y;
    int lin = blockIdx.y * nwgx + blockIdx.x;
    lin = (lin & 7) * (nwg >> 3) + (lin >> 3);   // bijective: nwg % 8 == 0
    const int m0 = (lin / nwgx) * 128, n0 = (lin % nwgx) * 128;
    const int lane = tid & 63, w = tid >> 6;
    const int quad = lane >> 4, c = lane & 15;
    const int wm = (w & 1) * 64, wn = (w >> 1) * 64;

    f32x4 acc[4][4];
#pragma unroll
    for (int i = 0; i < 4; i++)
#pragma unroll
        for (int j = 0; j < 4; j++) acc[i][j] = zero4();

    // staging: wave w covers rows [w*32, w*32+32) x 64 k per tile.
    // instr i: 8 rows (w*32+i*8+(lane>>3)), source col pre-swizzled (R18).
    const int srow = lane >> 3;                         // 0..7
    const int scol = ((lane & 7) ^ ((srow & 1) << 2)) * 8;  // pre-swizzled
    const size_t abase = (size_t)(m0 + w * 32 + srow) * K + scol;
    const size_t bbase = (size_t)(n0 + w * 32 + srow) * K + scol;
    u16* asl = &As[w * 32 * 64];   // wave-uniform LDS base
    u16* bsl = &Bs[w * 32 * 64];

    const int cpar = (c & 1) << 2;   // read-side swizzle term

    for (int k0 = 0; k0 < K; k0 += 64) {
        __syncthreads();           // previous iteration's frag reads done
#pragma unroll
        for (int i = 0; i < 4; i++)
            gload16(A + abase + (size_t)(i * 8) * K + k0, asl + i * 512);
#pragma unroll
        for (int i = 0; i < 4; i++)
            gload16(Bt + bbase + (size_t)(i * 8) * K + k0, bsl + i * 512);
        asm volatile("s_waitcnt vmcnt(0)" ::: "memory");  // tile landed in LDS
        __syncthreads();

        short8 af[4][2], bfr[4][2];
#pragma unroll
        for (int mi = 0; mi < 4; mi++)
#pragma unroll
            for (int kk = 0; kk < 2; kk++)
                af[mi][kk] = *(const short8*)
                    &As[(wm + mi * 16 + c) * 64 + (((kk * 4 + quad) ^ cpar) * 8)];
#pragma unroll
        for (int ni = 0; ni < 4; ni++)
#pragma unroll
            for (int kk = 0; kk < 2; kk++)
                bfr[ni][kk] = *(const short8*)
                    &Bs[(wn + ni * 16 + c) * 64 + (((kk * 4 + quad) ^ cpar) * 8)];
#pragma unroll
        for (int kk = 0; kk < 2; kk++)
#pragma unroll
            for (int mi = 0; mi < 4; mi++)
#pragma unroll
                for (int ni = 0; ni < 4; ni++)
                    acc[mi][ni] = __builtin_amdgcn_mfma_f32_16x16x32_bf16(
                        af[mi][kk], bfr[ni][kk], acc[mi][ni], 0, 0, 0);
    }

#pragma unroll
    for (int ni = 0; ni < 4; ni++) {
        const int gc = n0 + wn + ni * 16 + c;
        const float bv = bias[gc];
        if (MODE == 0) {
            const int which = gc / 768;
            const int e = gc - which * 768;
            const int hh = e >> 6, d = e & 63;
            u16* op = (which == 0) ? O0 : (which == 1 ? O1 : O2);
#pragma unroll
            for (int mi = 0; mi < 4; mi++)
#pragma unroll
                for (int r = 0; r < 4; r++) {
                    const int gr = m0 + wm + mi * 16 + quad * 4 + r;
                    const int bb = gr >> 11, s = gr & 2047;
                    op[(((size_t)bb * 12 + hh) * 2048 + s) * 64 + d] =
                        f2b(acc[mi][ni][r] + bv);
                }
        } else {
#pragma unroll
            for (int mi = 0; mi < 4; mi++)
#pragma unroll
                for (int r = 0; r < 4; r++) {
                    const int gr = m0 + wm + mi * 16 + quad * 4 + r;
                    Of[(size_t)gr * N + gc] = acc[mi][ni][r] + bv;
                }
        }
    }
}

// ---------------------------------------------------------------------------
// Flash attention, R23 = R22 minus the launch-bounds VGPR cap.
// R22 post-mortem: __launch_bounds__(256,4) forced VGPR 80->64 -> scratch
// spills (WRITE_SIZE 12288->18000 KB = +5.7 MB scratch; VALUBusy 35->41.7)
// while occupancy barely moved. The hint was never needed: LDS 40448 B fits
// 4 blocks/CU (4x40448 = 161792 <= 163840) and 16 waves x 80 VGPR = 320/SIMD
// <= 512 -> HW can pack the 4th block with the natural 80-VGPR allocation.
// bounds(256,3) restores the R17-proven register budget; msb bf16 mask
// (verified R22, absmax pass) keeps the LDS small.
// ---------------------------------------------------------------------------
__global__ __launch_bounds__(256, 3) void attn_kernel(
    const u16* __restrict__ Q, const u16* __restrict__ Kv,
    const u16* __restrict__ Vv, const int* __restrict__ attmask,
    u16* __restrict__ Y)
{
    const int S = 2048, D = 64, NH = 12;
    __shared__ u16 Ks[64][72];          // [pos][d]
    __shared__ u16 Vs[64][68];          // [d][pos]
    __shared__ u16 Ps[4][2][16][72];    // per-wave,per-group P: [qrow][pos]
    __shared__ u16 msb[2048];           // bf16 exp2-domain bias: 0 or -32768

    const int tid = threadIdx.x;
    const int w = tid >> 6, lane = tid & 63;
    const int quad = lane >> 4, c = lane & 15;
    const int bh = blockIdx.x;        // 0..47
    const int qt = blockIdx.y;        // 0..15
    const int b = bh / NH, h = bh - b * NH;

    const u16* Qh = Q + (size_t)bh * S * D;
    const u16* Kh = Kv + (size_t)bh * S * D;
    const u16* Vh = Vv + (size_t)bh * S * D;
    const int q0 = qt * 128 + w * 16;   // group 0; group 1 at q0+64

    short8 aq00 = *(const short8*)&Qh[(size_t)(q0 + c) * D + quad * 8];
    short8 aq01 = *(const short8*)&Qh[(size_t)(q0 + c) * D + 32 + quad * 8];
    short8 aq10 = *(const short8*)&Qh[(size_t)(q0 + 64 + c) * D + quad * 8];
    short8 aq11 = *(const short8*)&Qh[(size_t)(q0 + 64 + c) * D + 32 + quad * 8];

    // whole-sequence mask bias, bf16: 0xC700 = -32768 (exp2 -> exact 0)
    for (int i = tid; i < S; i += 256)
        msb[i] = (attmask[b * S + i] == 0) ? (u16)0xC700 : (u16)0;

    f32x4 o_acc[2][4];
#pragma unroll
    for (int g = 0; g < 2; g++)
#pragma unroll
        for (int i = 0; i < 4; i++) o_acc[g][i] = zero4();
    float l0 = 0.f, l1 = 0.f;

    const int kpos = tid >> 2, kd = (tid & 3) * 8;
    const int p2 = tid >> 3, vd = (tid & 7) * 8;

    // T14 prologue: issue tile-0 loads
    short8 k0r = *(const short8*)&Kh[(size_t)kpos * D + kd];
    short8 k1r = *(const short8*)&Kh[(size_t)kpos * D + kd + 32];
    short8 v0r = *(const short8*)&Vh[(size_t)(2 * p2) * D + vd];
    short8 v1r = *(const short8*)&Vh[(size_t)(2 * p2 + 1) * D + vd];

    const float SC = 0.18033688f;  // 0.125 * log2(e)

    for (int kt = 0; kt < S / 64; kt++) {
        // ---- staging (raw barriers: vmcnt NOT drained -> prefetch in flight)
        asm volatile("" ::: "memory");
        __builtin_amdgcn_s_barrier();
        asm volatile("" ::: "memory");
        *(short8*)&Ks[kpos][kd] = k0r;
        *(short8*)&Ks[kpos][kd + 32] = k1r;
#pragma unroll
        for (int j = 0; j < 8; j++) {
            u32 pk = (u32)(u16)v0r[j] | ((u32)(u16)v1r[j] << 16);
            *(u32*)&Vs[vd + j][2 * p2] = pk;
        }
        if (kt + 1 < S / 64) {
            const int nb = (kt + 1) * 64;
            k0r = *(const short8*)&Kh[(size_t)(nb + kpos) * D + kd];
            k1r = *(const short8*)&Kh[(size_t)(nb + kpos) * D + kd + 32];
            v0r = *(const short8*)&Vh[(size_t)(nb + 2 * p2) * D + vd];
            v1r = *(const short8*)&Vh[(size_t)(nb + 2 * p2 + 1) * D + vd];
        }
        asm volatile("s_waitcnt lgkmcnt(0)" ::: "memory");
        __builtin_amdgcn_s_barrier();
        asm volatile("" ::: "memory");

        const int kbase = kt * 64;

        // ---- QK^T, swapped: s[g][ni] = S[kpos=ni*16+quad*4+r][q-group g]
        f32x4 s0[4], s1[4];
#pragma unroll
        for (int ni = 0; ni < 4; ni++) { s0[ni] = zero4(); s1[ni] = zero4(); }
        __builtin_amdgcn_s_setprio(1);
#pragma unroll
        for (int ni = 0; ni < 4; ni++) {
            short8 bk0 = *(const short8*)&Ks[ni * 16 + c][quad * 8];
            short8 bk1 = *(const short8*)&Ks[ni * 16 + c][32 + quad * 8];
            s0[ni] = __builtin_amdgcn_mfma_f32_16x16x32_bf16(bk0, aq00, s0[ni], 0, 0, 0);
            s0[ni] = __builtin_amdgcn_mfma_f32_16x16x32_bf16(bk1, aq01, s0[ni], 0, 0, 0);
            s1[ni] = __builtin_amdgcn_mfma_f32_16x16x32_bf16(bk0, aq10, s1[ni], 0, 0, 0);
            s1[ni] = __builtin_amdgcn_mfma_f32_16x16x32_bf16(bk1, aq11, s1[ni], 0, 0, 0);
        }
        __builtin_amdgcn_s_setprio(0);

        // ---- softmax per group: bf16 bias expand + cvtpk + b64 stores ----
#pragma unroll
        for (int ni = 0; ni < 4; ni++) {
            const uint2 mb = *(const uint2*)&msb[kbase + ni * 16 + quad * 4];
            union { u32 i; float f; } e0, e1, e2, e3;
            e0.i = mb.x << 16; e1.i = mb.x & 0xffff0000u;
            e2.i = mb.y << 16; e3.i = mb.y & 0xffff0000u;
            {
                float p0 = fexp2(fmaf(s0[ni][0], SC, e0.f));
                float p1 = fexp2(fmaf(s0[ni][1], SC, e1.f));
                float p2f = fexp2(fmaf(s0[ni][2], SC, e2.f));
                float p3 = fexp2(fmaf(s0[ni][3], SC, e3.f));
                l0 += (p0 + p1) + (p2f + p3);
                uint2 pk;
                pk.x = cvtpk(p0, p1);
                pk.y = cvtpk(p2f, p3);
                *(uint2*)&Ps[w][0][c][ni * 16 + quad * 4] = pk;
            }
            {
                float p0 = fexp2(fmaf(s1[ni][0], SC, e0.f));
                float p1 = fexp2(fmaf(s1[ni][1], SC, e1.f));
                float p2f = fexp2(fmaf(s1[ni][2], SC, e2.f));
                float p3 = fexp2(fmaf(s1[ni][3], SC, e3.f));
                l1 += (p0 + p1) + (p2f + p3);
                uint2 pk;
                pk.x = cvtpk(p0, p1);
                pk.y = cvtpk(p2f, p3);
                *(uint2*)&Ps[w][1][c][ni * 16 + quad * 4] = pk;
            }
        }
        // Ps is per-wave: in-order DS pipeline orders stores before our reads.

        short8 ap00 = *(const short8*)&Ps[w][0][c][quad * 8];
        short8 ap01 = *(const short8*)&Ps[w][0][c][32 + quad * 8];
        short8 ap10 = *(const short8*)&Ps[w][1][c][quad * 8];
        short8 ap11 = *(const short8*)&Ps[w][1][c][32 + quad * 8];
        __builtin_amdgcn_s_setprio(1);
#pragma unroll
        for (int ni = 0; ni < 4; ni++) {
            union { short8 v8; s16x4 v4[2]; } u0, u1;
            u0.v4[0] = *(const s16x4*)&Vs[ni * 16 + c][quad * 8];
            u0.v4[1] = *(const s16x4*)&Vs[ni * 16 + c][quad * 8 + 4];
            u1.v4[0] = *(const s16x4*)&Vs[ni * 16 + c][32 + quad * 8];
            u1.v4[1] = *(const s16x4*)&Vs[ni * 16 + c][32 + quad * 8 + 4];
            o_acc[0][ni] = __builtin_amdgcn_mfma_f32_16x16x32_bf16(ap00, u0.v8, o_acc[0][ni], 0, 0, 0);
            o_acc[0][ni] = __builtin_amdgcn_mfma_f32_16x16x32_bf16(ap01, u1.v8, o_acc[0][ni], 0, 0, 0);
            o_acc[1][ni] = __builtin_amdgcn_mfma_f32_16x16x32_bf16(ap10, u0.v8, o_acc[1][ni], 0, 0, 0);
            o_acc[1][ni] = __builtin_amdgcn_mfma_f32_16x16x32_bf16(ap11, u1.v8, o_acc[1][ni], 0, 0, 0);
        }
        __builtin_amdgcn_s_setprio(0);
    }

    // full row-sums: quads hold disjoint kpos subsets of row c
    l0 += __shfl_xor(l0, 16);
    l0 += __shfl_xor(l0, 32);
    l1 += __shfl_xor(l1, 16);
    l1 += __shfl_xor(l1, 32);

    const size_t ybase = ((size_t)b * S) * 768 + h * 64;
#pragma unroll
    for (int r = 0; r < 4; r++) {
        const float lr0 = __shfl(l0, quad * 4 + r);
        const float lr1 = __shfl(l1, quad * 4 + r);
        const float inv0 = 1.f / fmaxf(lr0, 1e-30f);
        const float inv1 = 1.f / fmaxf(lr1, 1e-30f);
        const int srow0 = qt * 128 + w * 16 + quad * 4 + r;
        const int srow1 = srow0 + 64;
#pragma unroll
        for (int ni = 0; ni < 4; ni++) {
            Y[ybase + (size_t)srow0 * 768 + ni * 16 + c] = f2b(o_acc[0][ni][r] * inv0);
            Y[ybase + (size_t)srow1 * 768 + ni * 16 + c] = f2b(o_acc[1][ni][r] * inv1);
        }
    }
}

extern "C" void kernel_launch(void* const* d_in, const int* in_sizes, int n_in,
                              void* d_out, int out_size, void* d_ws, size_t ws_size,
                              hipStream_t stream) {
    const float* x     = (const float*)d_in[0];
    const int* attmask = (const int*)d_in[1];
    const float* Wqkv  = (const float*)d_in[2];
    const float* bqkv  = (const float*)d_in[3];
    const float* Wproj = (const float*)d_in[4];
    const float* bproj = (const float*)d_in[5];
    float* outf = (float*)d_out;

    // ws layout: bf16 staging + intermediates (all fully rewritten per launch)
    u16* base = (u16*)d_ws;
    const size_t nx = 4ull * 2048 * 768;       // 6,291,456
    const size_t nwqkv = 768ull * 2304;        // 1,769,472
    const size_t nwproj = 768ull * 768;        // 589,824
    u16* xb     = base;
    u16* Wqkvb  = xb + nx;          // TRANSPOSED: [2304][768]
    u16* Wprojb = Wqkvb + nwqkv;    // TRANSPOSED: [768][768]
    u16* Qb     = Wprojb + nwproj;
    const size_t headElems = 48ull * 2048 * 64;  // 6,291,456
    u16* Kb = Qb + headElems;
    u16* Vb = Kb + headElems;
    u16* Yb = Vb + headElems;

    // single prep launch: both weight transposes + x convert
    prep_kernel<<<1152, 256, 0, stream>>>(x, xb, Wqkv, Wqkvb, Wproj, Wprojb,
                                          (int)(nx / 8));

    // QKV GEMM: [8192,768] x [2304,768]^T + bias -> Q/K/V [b,h,s,d] bf16
    gemm_bt_kernel<0><<<dim3(18, 64), 256, 0, stream>>>(
        xb, Wqkvb, bqkv, Qb, Kb, Vb, nullptr, 8192, 2304, 768);
    // Flash attention -> Y [b,s,768] bf16 (128 q-rows per block)
    attn_kernel<<<dim3(48, 16), 256, 0, stream>>>(Qb, Kb, Vb, attmask, Yb);
    // Proj GEMM: [8192,768] x [768,768]^T + bias -> d_out fp32
    gemm_bt_kernel<1><<<dim3(6, 64), 256, 0, stream>>>(
        Yb, Wprojb, bproj, nullptr, nullptr, nullptr, outf, 8192, 768, 768);
}